// Round 1
// baseline (459.249 us; speedup 1.0000x reference)
//
#include <hip/hip_runtime.h>
#include <math.h>

#define N_PIX 4096
#define CCH 32
#define BB 2

// ---------------------------------------------------------------------------
// Conv 3x3 SAME + bias + ReLU, Cout=32 fixed, fp32.
// Block = one (batch,row) for one weight-set (blockIdx.y selects among 3).
// 256 threads: px = t&63 (column), g = t>>6 selects 8 output channels.
// Input channels processed in chunks of 16 staged in LDS with halo rows;
// weights staged transposed to [ci][kk][co] so 8 couts load as 2 x float4.
// ---------------------------------------------------------------------------
struct ConvArgs {
  const float* in0[3];
  const float* in1[3];   // optional second input (concat), may be null
  const float* w[3];
  const float* bias[3];
  float* out[3];
  int cin0, cin1;
};

__global__ __launch_bounds__(256) void conv3_relu(ConvArgs a)
{
  const int sel = blockIdx.y;
  const int b = blockIdx.x >> 6;
  const int y = blockIdx.x & 63;
  const float* __restrict__ in0  = a.in0[sel];
  const float* __restrict__ in1  = a.in1[sel];
  const float* __restrict__ w    = a.w[sel];
  const float* __restrict__ bias = a.bias[sel];
  float* __restrict__ out        = a.out[sel];
  const int cin0 = a.cin0, cin1 = a.cin1, cinT = cin0 + cin1;

  __shared__ __align__(16) float xs[16*3*66];   // [ci][r][col(66, zero-padded)]
  __shared__ __align__(16) float wl[16*9*32];   // [ci][kk][co]

  const int t  = threadIdx.x;
  const int px = t & 63;
  const int g  = t >> 6;

  float acc[8] = {0.f,0.f,0.f,0.f,0.f,0.f,0.f,0.f};

  for (int cb = 0; cb < cinT; cb += 16) {
    // stage input chunk (rows y-1..y+1, cols padded)
    for (int j = t; j < 16*3*66; j += 256) {
      int ci  = j / 198;
      int rem = j - ci*198;
      int r   = rem / 66;
      int col = rem - r*66;
      int yy = y + r - 1;
      int xx = col - 1;
      float vv = 0.f;
      if ((unsigned)yy < 64u && (unsigned)xx < 64u) {
        int ch = cb + ci;
        vv = (ch < cin0)
           ? in0[((size_t)(b*cin0 + ch)*64 + yy)*64 + xx]
           : in1[((size_t)(b*cin1 + (ch-cin0))*64 + yy)*64 + xx];
      }
      xs[j] = vv;
    }
    // stage weights transposed: wl[(ci*9+kk)*32+co] = w[(co*cinT + cb+ci)*9 + kk]
    for (int j = t; j < 16*9*32; j += 256) {
      int co = j & 31;
      int kk = (j >> 5) % 9;
      int ci = j / 288;
      wl[j] = w[((size_t)co*cinT + (cb+ci))*9 + kk];
    }
    __syncthreads();
    #pragma unroll 4
    for (int ci = 0; ci < 16; ++ci) {
      float xv[9];
      #pragma unroll
      for (int r = 0; r < 3; ++r)
        #pragma unroll
        for (int kx = 0; kx < 3; ++kx)
          xv[r*3+kx] = xs[(ci*3+r)*66 + px + kx];
      #pragma unroll
      for (int kk = 0; kk < 9; ++kk) {
        const float4 wa = *(const float4*)&wl[(ci*9+kk)*32 + g*8];
        const float4 wb = *(const float4*)&wl[(ci*9+kk)*32 + g*8 + 4];
        const float xk = xv[kk];
        acc[0] += xk*wa.x; acc[1] += xk*wa.y; acc[2] += xk*wa.z; acc[3] += xk*wa.w;
        acc[4] += xk*wb.x; acc[5] += xk*wb.y; acc[6] += xk*wb.z; acc[7] += xk*wb.w;
      }
    }
    __syncthreads();
  }
  #pragma unroll
  for (int co = 0; co < 8; ++co) {
    float r = acc[co] + bias[g*8 + co];
    out[((size_t)(b*32 + g*8 + co)*64 + y)*64 + px] = fmaxf(r, 0.f);
  }
}

// ---------------------------------------------------------------------------
// Fused flash-style attention pass, fp32.
// out[c][n] = sum_m softmax_m(scale * sum_c' X[c'][n] Y[c'][m]) * Z[c][m]
// blockIdx.x = 32-row query block, blockIdx.y = pass (0,1,2), blockIdx.z = batch.
// Key-tile TM=128; register-tiled 4x4 outer products for both GEMMs.
// ---------------------------------------------------------------------------
__global__ __launch_bounds__(256) void attn_pass(
    const float* __restrict__ q, const float* __restrict__ k, const float* __restrict__ v,
    float* __restrict__ oA, float* __restrict__ oB, float* __restrict__ oC)
{
  const int pass = blockIdx.y;
  const int b = blockIdx.z;
  const int n0 = blockIdx.x * 32;
  const float* X; const float* Y; const float* Z; float* O;
  if (pass == 0)      { X = q; Y = k; Z = v; O = oA; }
  else if (pass == 1) { X = k; Y = v; Z = q; O = oB; }
  else                { X = v; Y = q; Z = k; O = oC; }
  const size_t boff = (size_t)b * CCH * N_PIX;
  X += boff; Y += boff; Z += boff; O += boff;

  __shared__ __align__(16) float XT[32][36];   // XT[c][i] = X[c][n0+i]
  __shared__ __align__(16) float U[4608];      // union: Yl[c][mm] stride 132 / Zt[m][c] stride 36
  __shared__ __align__(16) float St[128][36];  // S / P tile, [m][i]
  __shared__ float red[8][32];
  __shared__ float mx[32], sm[32], corr[32];

  const int t = threadIdx.x;
  const int iq4  = (t >> 5) * 4;        // i-quad (phase A and B)
  const int mq4  = (t & 31) * 4;        // m-quad (phase A)
  const int cq4  = ((t >> 2) & 7) * 4;  // c-quad (phase B)
  const int msub = t & 3;               // m sub-lane (phase B)

  for (int j = t; j < 32*32; j += 256) {
    int c = j >> 5, i = j & 31;
    XT[c][i] = X[(size_t)c*N_PIX + n0 + i];
  }
  if (t < 32) { mx[t] = -INFINITY; sm[t] = 0.f; }
  float acc[16];
  #pragma unroll
  for (int z = 0; z < 16; ++z) acc[z] = 0.f;
  __syncthreads();

  for (int m0 = 0; m0 < N_PIX; m0 += 128) {
    // ---- stage Y tile: Yl[c][mm], row stride 132 ----
    for (int j = t; j < 32*128; j += 256) {
      int c = j >> 7, mm = j & 127;
      U[c*132 + mm] = Y[(size_t)c*N_PIX + m0 + mm];
    }
    __syncthreads();
    // ---- phase A: S[i][m] = scale * sum_c XT[c][i]*Y[c][m], stored St[m][i] ----
    float s[16];
    #pragma unroll
    for (int z = 0; z < 16; ++z) s[z] = 0.f;
    #pragma unroll
    for (int c = 0; c < 32; ++c) {
      const float4 x4 = *(const float4*)&XT[c][iq4];
      const float4 y4 = *(const float4*)&U[c*132 + mq4];
      s[0]+=x4.x*y4.x;  s[1]+=x4.x*y4.y;  s[2]+=x4.x*y4.z;  s[3]+=x4.x*y4.w;
      s[4]+=x4.y*y4.x;  s[5]+=x4.y*y4.y;  s[6]+=x4.y*y4.z;  s[7]+=x4.y*y4.w;
      s[8]+=x4.z*y4.x;  s[9]+=x4.z*y4.y;  s[10]+=x4.z*y4.z; s[11]+=x4.z*y4.w;
      s[12]+=x4.w*y4.x; s[13]+=x4.w*y4.y; s[14]+=x4.w*y4.z; s[15]+=x4.w*y4.w;
    }
    const float SC = 0.17677669529663687f;  // 32^-0.5
    #pragma unroll
    for (int mj = 0; mj < 4; ++mj) {
      float4 o;
      o.x = s[0+mj]*SC; o.y = s[4+mj]*SC; o.z = s[8+mj]*SC; o.w = s[12+mj]*SC;
      *(float4*)&St[mq4+mj][iq4] = o;
    }
    __syncthreads();
    // ---- softmax: tile row max ----
    {
      int i = t & 31, seg = t >> 5;
      float lm = -INFINITY;
      #pragma unroll
      for (int mm = 0; mm < 16; ++mm) lm = fmaxf(lm, St[seg*16+mm][i]);
      red[seg][i] = lm;
    }
    __syncthreads();
    if (t < 32) {
      float m8 = red[0][t];
      #pragma unroll
      for (int s8 = 1; s8 < 8; ++s8) m8 = fmaxf(m8, red[s8][t]);
      float nm = fmaxf(mx[t], m8);
      corr[t] = __expf(mx[t] - nm);
      mx[t] = nm;
    }
    __syncthreads();
    // ---- P = exp(S - max), partial sums; also stage Z tile (transposed) ----
    {
      int i = t & 31, seg = t >> 5;
      const float nm = mx[i];
      float ls = 0.f;
      #pragma unroll
      for (int mm = 0; mm < 16; ++mm) {
        int m = seg*16 + mm;
        float p = __expf(St[m][i] - nm);
        St[m][i] = p;
        ls += p;
      }
      red[seg][i] = ls;
    }
    for (int j = t; j < 32*128; j += 256) {      // Zt[m][c], stride 36
      int c = j >> 7, mm = j & 127;
      U[mm*36 + c] = Z[(size_t)c*N_PIX + m0 + mm];
    }
    __syncthreads();
    if (t < 32) {
      float s8 = red[0][t];
      #pragma unroll
      for (int q8 = 1; q8 < 8; ++q8) s8 += red[q8][t];
      sm[t] = sm[t]*corr[t] + s8;
    }
    // ---- phase B: rescale acc, accumulate P * Z^T ----
    {
      const float c0 = corr[iq4], c1 = corr[iq4+1], c2 = corr[iq4+2], c3 = corr[iq4+3];
      acc[0]*=c0;  acc[1]*=c0;  acc[2]*=c0;  acc[3]*=c0;
      acc[4]*=c1;  acc[5]*=c1;  acc[6]*=c1;  acc[7]*=c1;
      acc[8]*=c2;  acc[9]*=c2;  acc[10]*=c2; acc[11]*=c2;
      acc[12]*=c3; acc[13]*=c3; acc[14]*=c3; acc[15]*=c3;
      #pragma unroll
      for (int ms = 0; ms < 32; ++ms) {
        int m = ms*4 + msub;
        const float4 p4 = *(const float4*)&St[m][iq4];      // P over i-quad
        const float4 z4 = *(const float4*)&U[m*36 + cq4];   // Z over c-quad
        acc[0]+=p4.x*z4.x;  acc[1]+=p4.x*z4.y;  acc[2]+=p4.x*z4.z;  acc[3]+=p4.x*z4.w;
        acc[4]+=p4.y*z4.x;  acc[5]+=p4.y*z4.y;  acc[6]+=p4.y*z4.z;  acc[7]+=p4.y*z4.w;
        acc[8]+=p4.z*z4.x;  acc[9]+=p4.z*z4.y;  acc[10]+=p4.z*z4.z; acc[11]+=p4.z*z4.w;
        acc[12]+=p4.w*z4.x; acc[13]+=p4.w*z4.y; acc[14]+=p4.w*z4.z; acc[15]+=p4.w*z4.w;
      }
    }
    __syncthreads();
  }
  // ---- reduce partial accs over msub (4 threads per (i,c)) via LDS ----
  float* redbig = &St[0][0];   // 4*32*36 = 4608 floats, fits
  #pragma unroll
  for (int ij = 0; ij < 4; ++ij) {
    float4 o;
    o.x = acc[ij*4+0]; o.y = acc[ij*4+1]; o.z = acc[ij*4+2]; o.w = acc[ij*4+3];
    *(float4*)&redbig[(msub*32 + iq4 + ij)*36 + cq4] = o;
  }
  __syncthreads();
  {
    const int c  = t >> 3;
    const int ib = (t & 7) * 4;
    #pragma unroll
    for (int ii = 0; ii < 4; ++ii) {
      int i = ib + ii;
      float ssum = redbig[(i)*36 + c] + redbig[(32+i)*36 + c]
                 + redbig[(64+i)*36 + c] + redbig[(96+i)*36 + c];
      O[(size_t)c*N_PIX + n0 + i] = ssum / sm[i];
    }
  }
}

// ---------------------------------------------------------------------------
__global__ void avg3_k(const float* __restrict__ a, const float* __restrict__ b,
                       const float* __restrict__ c, float* __restrict__ o, int n)
{
  int i = blockIdx.x * 256 + threadIdx.x;
  if (i < n) o[i] = (a[i] + b[i] + c[i]) * (1.0f/3.0f);
}

// ---------------------------------------------------------------------------
extern "C" void kernel_launch(void* const* d_in, const int* in_sizes, int n_in,
                              void* d_out, int out_size, void* d_ws, size_t ws_size,
                              hipStream_t stream)
{
  const float* x   = (const float*)d_in[0];
  const float* wq1 = (const float*)d_in[1];  const float* bq1 = (const float*)d_in[2];
  const float* wq2 = (const float*)d_in[3];  const float* bq2 = (const float*)d_in[4];
  const float* wk1 = (const float*)d_in[5];  const float* bk1 = (const float*)d_in[6];
  const float* wk2 = (const float*)d_in[7];  const float* bk2 = (const float*)d_in[8];
  const float* wv1 = (const float*)d_in[9];  const float* bv1 = (const float*)d_in[10];
  const float* wv2 = (const float*)d_in[11]; const float* bv2 = (const float*)d_in[12];
  const float* wr  = (const float*)d_in[13]; const float* br  = (const float*)d_in[14];
  const float* wg  = (const float*)d_in[15]; const float* bg  = (const float*)d_in[16];
  const float* wb_ = (const float*)d_in[17]; const float* bb_ = (const float*)d_in[18];
  const float* w2  = (const float*)d_in[19]; const float* b2  = (const float*)d_in[20];
  const float* w3  = (const float*)d_in[21]; const float* b3  = (const float*)d_in[22];

  float* ws = (float*)d_ws;
  const size_t SLOT = (size_t)BB * CCH * N_PIX;   // 262144 floats = 1 MB
  float* s0 = ws + 0*SLOT;
  float* s1 = ws + 1*SLOT;
  float* s2 = ws + 2*SLOT;
  float* s3 = ws + 3*SLOT;
  float* s4 = ws + 4*SLOT;
  float* s5 = ws + 5*SLOT;
  float* s6 = ws + 6*SLOT;
  float* s7 = ws + 7*SLOT;
  float* s8 = ws + 8*SLOT;

  // stage 1: x -> q1,k1,v1 (Cin=64)
  ConvArgs a1;
  a1.in0[0]=x; a1.in0[1]=x; a1.in0[2]=x;
  a1.in1[0]=nullptr; a1.in1[1]=nullptr; a1.in1[2]=nullptr;
  a1.w[0]=wq1; a1.w[1]=wk1; a1.w[2]=wv1;
  a1.bias[0]=bq1; a1.bias[1]=bk1; a1.bias[2]=bv1;
  a1.out[0]=s0; a1.out[1]=s1; a1.out[2]=s2;
  a1.cin0=64; a1.cin1=0;
  conv3_relu<<<dim3(BB*64,3), dim3(256), 0, stream>>>(a1);

  // stage 2: -> q,k,v (Cin=32)
  ConvArgs a2;
  a2.in0[0]=s0; a2.in0[1]=s1; a2.in0[2]=s2;
  a2.in1[0]=nullptr; a2.in1[1]=nullptr; a2.in1[2]=nullptr;
  a2.w[0]=wq2; a2.w[1]=wk2; a2.w[2]=wv2;
  a2.bias[0]=bq2; a2.bias[1]=bk2; a2.bias[2]=bv2;
  a2.out[0]=s3; a2.out[1]=s4; a2.out[2]=s5;
  a2.cin0=32; a2.cin1=0;
  conv3_relu<<<dim3(BB*64,3), dim3(256), 0, stream>>>(a2);

  // attention: 3 passes x 2 batches -> ctx raw into s0,s1,s2
  attn_pass<<<dim3(N_PIX/32, 3, BB), dim3(256), 0, stream>>>(s3, s4, s5, s0, s1, s2);

  // per-pass output convs (Cin=32)
  ConvArgs a3;
  a3.in0[0]=s0; a3.in0[1]=s1; a3.in0[2]=s2;
  a3.in1[0]=nullptr; a3.in1[1]=nullptr; a3.in1[2]=nullptr;
  a3.w[0]=wr; a3.w[1]=wg; a3.w[2]=wb_;
  a3.bias[0]=br; a3.bias[1]=bg; a3.bias[2]=bb_;
  a3.out[0]=s6; a3.out[1]=s7; a3.out[2]=s8;
  a3.cin0=32; a3.cin1=0;
  conv3_relu<<<dim3(BB*64,3), dim3(256), 0, stream>>>(a3);

  // ctx = (r+g+b)/3 -> s3
  avg3_k<<<dim3((int)(SLOT/256)), dim3(256), 0, stream>>>(s6, s7, s8, s3, (int)SLOT);

  // out = conv(concat(x, ctx), w2)   (Cin = 64 + 32)
  ConvArgs a4;
  a4.in0[0]=x; a4.in0[1]=x; a4.in0[2]=x;
  a4.in1[0]=s3; a4.in1[1]=s3; a4.in1[2]=s3;
  a4.w[0]=w2; a4.w[1]=w2; a4.w[2]=w2;
  a4.bias[0]=b2; a4.bias[1]=b2; a4.bias[2]=b2;
  a4.out[0]=s4; a4.out[1]=s4; a4.out[2]=s4;
  a4.cin0=64; a4.cin1=32;
  conv3_relu<<<dim3(BB*64,1), dim3(256), 0, stream>>>(a4);

  // out = conv(out, w3) -> d_out
  ConvArgs a5;
  a5.in0[0]=s4; a5.in0[1]=s4; a5.in0[2]=s4;
  a5.in1[0]=nullptr; a5.in1[1]=nullptr; a5.in1[2]=nullptr;
  a5.w[0]=w3; a5.w[1]=w3; a5.w[2]=w3;
  a5.bias[0]=b3; a5.bias[1]=b3; a5.bias[2]=b3;
  a5.out[0]=(float*)d_out; a5.out[1]=(float*)d_out; a5.out[2]=(float*)d_out;
  a5.cin0=32; a5.cin1=0;
  conv3_relu<<<dim3(BB*64,1), dim3(256), 0, stream>>>(a5);
}

// Round 3
// 304.158 us; speedup vs baseline: 1.5099x; 1.5099x over previous
//
#include <hip/hip_runtime.h>
#include <hip/hip_bf16.h>
#include <math.h>

#define N_PIX 4096
#define CCH 32
#define BB 2

typedef __attribute__((ext_vector_type(8))) short short8;
typedef __attribute__((ext_vector_type(4))) float f32x4;

// ---------------------------------------------------------------------------
// Conv 3x3 SAME + bias + ReLU, Cout=32 fixed, fp32. (unchanged from R1)
// ---------------------------------------------------------------------------
struct ConvArgs {
  const float* in0[3];
  const float* in1[3];   // optional second input (concat), may be null
  const float* w[3];
  const float* bias[3];
  float* out[3];
  int cin0, cin1;
};

__global__ __launch_bounds__(256) void conv3_relu(ConvArgs a)
{
  const int sel = blockIdx.y;
  const int b = blockIdx.x >> 6;
  const int y = blockIdx.x & 63;
  const float* __restrict__ in0  = a.in0[sel];
  const float* __restrict__ in1  = a.in1[sel];
  const float* __restrict__ w    = a.w[sel];
  const float* __restrict__ bias = a.bias[sel];
  float* __restrict__ out        = a.out[sel];
  const int cin0 = a.cin0, cin1 = a.cin1, cinT = cin0 + cin1;

  __shared__ __align__(16) float xs[16*3*66];   // [ci][r][col(66, zero-padded)]
  __shared__ __align__(16) float wl[16*9*32];   // [ci][kk][co]

  const int t  = threadIdx.x;
  const int px = t & 63;
  const int g  = t >> 6;

  float acc[8] = {0.f,0.f,0.f,0.f,0.f,0.f,0.f,0.f};

  for (int cb = 0; cb < cinT; cb += 16) {
    for (int j = t; j < 16*3*66; j += 256) {
      int ci  = j / 198;
      int rem = j - ci*198;
      int r   = rem / 66;
      int col = rem - r*66;
      int yy = y + r - 1;
      int xx = col - 1;
      float vv = 0.f;
      if ((unsigned)yy < 64u && (unsigned)xx < 64u) {
        int ch = cb + ci;
        vv = (ch < cin0)
           ? in0[((size_t)(b*cin0 + ch)*64 + yy)*64 + xx]
           : in1[((size_t)(b*cin1 + (ch-cin0))*64 + yy)*64 + xx];
      }
      xs[j] = vv;
    }
    for (int j = t; j < 16*9*32; j += 256) {
      int co = j & 31;
      int kk = (j >> 5) % 9;
      int ci = j / 288;
      wl[j] = w[((size_t)co*cinT + (cb+ci))*9 + kk];
    }
    __syncthreads();
    #pragma unroll 4
    for (int ci = 0; ci < 16; ++ci) {
      float xv[9];
      #pragma unroll
      for (int r = 0; r < 3; ++r)
        #pragma unroll
        for (int kx = 0; kx < 3; ++kx)
          xv[r*3+kx] = xs[(ci*3+r)*66 + px + kx];
      #pragma unroll
      for (int kk = 0; kk < 9; ++kk) {
        const float4 wa = *(const float4*)&wl[(ci*9+kk)*32 + g*8];
        const float4 wb = *(const float4*)&wl[(ci*9+kk)*32 + g*8 + 4];
        const float xk = xv[kk];
        acc[0] += xk*wa.x; acc[1] += xk*wa.y; acc[2] += xk*wa.z; acc[3] += xk*wa.w;
        acc[4] += xk*wb.x; acc[5] += xk*wb.y; acc[6] += xk*wb.z; acc[7] += xk*wb.w;
      }
    }
    __syncthreads();
  }
  #pragma unroll
  for (int co = 0; co < 8; ++co) {
    float r = acc[co] + bias[g*8 + co];
    out[((size_t)(b*32 + g*8 + co)*64 + y)*64 + px] = fmaxf(r, 0.f);
  }
}

// ---------------------------------------------------------------------------
// Convert q,k,v fp32 [b][32][4096] -> bf16 direct [b][32][4096] AND
// transposed [b][4096][32].
// ---------------------------------------------------------------------------
__global__ __launch_bounds__(256) void cvt_qkv(
    const float* __restrict__ q, const float* __restrict__ k, const float* __restrict__ v,
    __hip_bfloat16* __restrict__ qDb, __hip_bfloat16* __restrict__ kDb, __hip_bfloat16* __restrict__ vDb,
    __hip_bfloat16* __restrict__ qTb, __hip_bfloat16* __restrict__ kTb, __hip_bfloat16* __restrict__ vTb)
{
  const int arr = blockIdx.y, b = blockIdx.z;
  const int n0 = blockIdx.x * 64;
  const float* src = (arr == 0 ? q : arr == 1 ? k : v) + (size_t)b*CCH*N_PIX;
  __hip_bfloat16* dD = (arr == 0 ? qDb : arr == 1 ? kDb : vDb) + (size_t)b*CCH*N_PIX;
  __hip_bfloat16* dT = (arr == 0 ? qTb : arr == 1 ? kTb : vTb) + (size_t)b*CCH*N_PIX;

  __shared__ float ls[32][65];
  const int t = threadIdx.x;
  for (int j = t; j < 2048; j += 256) {
    int c = j >> 6, n = j & 63;
    float vv = src[(size_t)c*N_PIX + n0 + n];
    dD[(size_t)c*N_PIX + n0 + n] = __float2bfloat16(vv);
    ls[c][n] = vv;
  }
  __syncthreads();
  for (int j = t; j < 2048; j += 256) {
    int n = j >> 5, c = j & 31;
    dT[(size_t)(n0 + n)*CCH + c] = __float2bfloat16(ls[c][n]);
  }
}

// ---------------------------------------------------------------------------
// MFMA flash attention pass (bf16 inputs, fp32 accumulate/output).
// out[c][n] = sum_m softmax_m(scale * sum_c' X[c'][n] Y[c'][m]) * Z[c][m]
// Per wave: 16 query rows (MFMA M=16), online softmax in registers.
//   GEMM1: A = X^T rows (from transposed array), B = Y^T rows -> S[i][m]
//          D layout: col m = lane&15, row i = (lane>>4)*4+reg  (m89-verified)
//   GEMM2: A = P from LDS (row i = lane&15, k m contiguous), B = Z[c][m]
// m-dim split across wave pairs; flash-decoding merge at the end.
// blockIdx.x: 32-row block (2 row-groups x 2 m-halves = 4 waves);
// blockIdx.y: pass; blockIdx.z: batch.
// ---------------------------------------------------------------------------
__global__ __launch_bounds__(256) void attn_mfma(
    const __hip_bfloat16* __restrict__ qD, const __hip_bfloat16* __restrict__ kD,
    const __hip_bfloat16* __restrict__ vD,
    const __hip_bfloat16* __restrict__ qT, const __hip_bfloat16* __restrict__ kT,
    const __hip_bfloat16* __restrict__ vT,
    float* __restrict__ oA, float* __restrict__ oB, float* __restrict__ oC)
{
  const int pass = blockIdx.y, b = blockIdx.z;
  const __hip_bfloat16 *XT, *YT, *ZD; float* O;
  if (pass == 0)      { XT = qT; YT = kT; ZD = vD; O = oA; }
  else if (pass == 1) { XT = kT; YT = vT; ZD = qD; O = oB; }
  else                { XT = vT; YT = qT; ZD = kD; O = oC; }
  const size_t boff = (size_t)b * CCH * N_PIX;
  XT += boff; YT += boff; ZD += boff; O += boff;

  const int t = threadIdx.x;
  const int wave = t >> 6, lane = t & 63;
  const int l15 = lane & 15, q4 = lane >> 4;
  const int rg = wave >> 1;          // row group within block
  const int half = wave & 1;         // m half
  const int n0 = blockIdx.x * 32 + rg * 16;
  const int mbase = half * (N_PIX/2);

  __shared__ __align__(16) __hip_bfloat16 Pt[4][16][136];  // per-wave P tile
  __shared__ float mg[2][64][16];                          // merge buffer per pair

  // A fragment for GEMM1: rows n0+l15, k = c = q4*8..q4*8+7 (hoisted, constant)
  const short8 a_x = *(const short8*)&XT[(size_t)(n0 + l15)*CCH + q4*8];

  f32x4 oacc0 = {0.f,0.f,0.f,0.f}, oacc1 = {0.f,0.f,0.f,0.f};
  float mx[4] = {-1e30f,-1e30f,-1e30f,-1e30f};
  float sm[4] = {0.f,0.f,0.f,0.f};
  const float SC2 = 0.1767766952966369f * 1.4426950408889634f;  // 32^-0.5 * log2(e)
  const f32x4 zf = {0.f,0.f,0.f,0.f};

  for (int m0 = mbase; m0 < mbase + N_PIX/2; m0 += 128) {
    // ---- GEMM1: S tile [16 i][128 m] ----
    f32x4 s[8];
    #pragma unroll
    for (int ml = 0; ml < 8; ++ml) {
      const short8 b_y = *(const short8*)&YT[(size_t)(m0 + ml*16 + l15)*CCH + q4*8];
      s[ml] = __builtin_amdgcn_mfma_f32_16x16x32_bf16(a_x, b_y, zf, 0, 0, 0);
    }
    // ---- online softmax: row max (reduce over 8 subtiles + 16 lanes) ----
    float corr[4];
    #pragma unroll
    for (int r = 0; r < 4; ++r) {
      float tm = s[0][r];
      #pragma unroll
      for (int ml = 1; ml < 8; ++ml) tm = fmaxf(tm, s[ml][r]);
      tm *= SC2;
      tm = fmaxf(tm, __shfl_xor(tm, 1));
      tm = fmaxf(tm, __shfl_xor(tm, 2));
      tm = fmaxf(tm, __shfl_xor(tm, 4));
      tm = fmaxf(tm, __shfl_xor(tm, 8));
      float nm = fmaxf(mx[r], tm);
      corr[r] = exp2f(mx[r] - nm);
      mx[r] = nm;
    }
    // ---- P = exp2(s*SC2 - mx), write bf16 to LDS, row sums ----
    float rs[4] = {0.f,0.f,0.f,0.f};
    #pragma unroll
    for (int ml = 0; ml < 8; ++ml) {
      #pragma unroll
      for (int r = 0; r < 4; ++r) {
        float p = exp2f(s[ml][r]*SC2 - mx[r]);
        rs[r] += p;
        Pt[wave][q4*4 + r][ml*16 + l15] = __float2bfloat16(p);
      }
    }
    #pragma unroll
    for (int r = 0; r < 4; ++r) {
      float v = rs[r];
      v += __shfl_xor(v, 1);
      v += __shfl_xor(v, 2);
      v += __shfl_xor(v, 4);
      v += __shfl_xor(v, 8);
      sm[r] = sm[r]*corr[r] + v;
      oacc0[r] *= corr[r];
      oacc1[r] *= corr[r];
    }
    // ---- GEMM2: O[i][c] += P[i][m] * Z[c][m] ----
    #pragma unroll
    for (int km = 0; km < 4; ++km) {
      const short8 a_p  = *(const short8*)&Pt[wave][l15][km*32 + q4*8];
      const short8 b_z0 = *(const short8*)&ZD[(size_t)l15*N_PIX        + m0 + km*32 + q4*8];
      const short8 b_z1 = *(const short8*)&ZD[(size_t)(16 + l15)*N_PIX + m0 + km*32 + q4*8];
      oacc0 = __builtin_amdgcn_mfma_f32_16x16x32_bf16(a_p, b_z0, oacc0, 0, 0, 0);
      oacc1 = __builtin_amdgcn_mfma_f32_16x16x32_bf16(a_p, b_z1, oacc1, 0, 0, 0);
    }
  }

  // ---- merge the two m-halves (flash-decoding style), write out ----
  if (half == 0) {
    #pragma unroll
    for (int r = 0; r < 4; ++r) {
      mg[rg][lane][r]      = oacc0[r];
      mg[rg][lane][4 + r]  = oacc1[r];
      mg[rg][lane][8 + r]  = mx[r];
      mg[rg][lane][12 + r] = sm[r];
    }
  }
  __syncthreads();
  if (half == 1) {
    #pragma unroll
    for (int r = 0; r < 4; ++r) {
      float mx0 = mg[rg][lane][8 + r], sm0 = mg[rg][lane][12 + r];
      float M = fmaxf(mx0, mx[r]);
      float c0 = exp2f(mx0 - M), c1 = exp2f(mx[r] - M);
      float S = sm0*c0 + sm[r]*c1;
      float inv = 1.0f / S;
      float o0 = (mg[rg][lane][r]     *c0 + oacc0[r]*c1) * inv;
      float o1 = (mg[rg][lane][4 + r] *c0 + oacc1[r]*c1) * inv;
      O[(size_t)l15*N_PIX        + n0 + q4*4 + r] = o0;
      O[(size_t)(16 + l15)*N_PIX + n0 + q4*4 + r] = o1;
    }
  }
}

// ---------------------------------------------------------------------------
__global__ void avg3_k(const float* __restrict__ a, const float* __restrict__ b,
                       const float* __restrict__ c, float* __restrict__ o, int n)
{
  int i = blockIdx.x * 256 + threadIdx.x;
  if (i < n) o[i] = (a[i] + b[i] + c[i]) * (1.0f/3.0f);
}

// ---------------------------------------------------------------------------
extern "C" void kernel_launch(void* const* d_in, const int* in_sizes, int n_in,
                              void* d_out, int out_size, void* d_ws, size_t ws_size,
                              hipStream_t stream)
{
  const float* x   = (const float*)d_in[0];
  const float* wq1 = (const float*)d_in[1];  const float* bq1 = (const float*)d_in[2];
  const float* wq2 = (const float*)d_in[3];  const float* bq2 = (const float*)d_in[4];
  const float* wk1 = (const float*)d_in[5];  const float* bk1 = (const float*)d_in[6];
  const float* wk2 = (const float*)d_in[7];  const float* bk2 = (const float*)d_in[8];
  const float* wv1 = (const float*)d_in[9];  const float* bv1 = (const float*)d_in[10];
  const float* wv2 = (const float*)d_in[11]; const float* bv2 = (const float*)d_in[12];
  const float* wr  = (const float*)d_in[13]; const float* br  = (const float*)d_in[14];
  const float* wg  = (const float*)d_in[15]; const float* bg  = (const float*)d_in[16];
  const float* wb_ = (const float*)d_in[17]; const float* bb_ = (const float*)d_in[18];
  const float* w2  = (const float*)d_in[19]; const float* b2  = (const float*)d_in[20];
  const float* w3  = (const float*)d_in[21]; const float* b3  = (const float*)d_in[22];

  float* ws = (float*)d_ws;
  const size_t SLOT = (size_t)BB * CCH * N_PIX;   // 262144 floats = 1 MB
  float* s0 = ws + 0*SLOT;
  float* s1 = ws + 1*SLOT;
  float* s2 = ws + 2*SLOT;
  float* s3 = ws + 3*SLOT;
  float* s4 = ws + 4*SLOT;
  float* s5 = ws + 5*SLOT;
  float* s6 = ws + 6*SLOT;
  float* s7 = ws + 7*SLOT;
  float* s8 = ws + 8*SLOT;

  // bf16 q/k/v (direct + transposed) overlay slots s6..s8 (free until stage 3)
  __hip_bfloat16* bfbase = (__hip_bfloat16*)s6;
  const size_t BSLOT = SLOT;                       // elements per bf16 array
  __hip_bfloat16* qDb = bfbase + 0*BSLOT;
  __hip_bfloat16* kDb = bfbase + 1*BSLOT;
  __hip_bfloat16* vDb = bfbase + 2*BSLOT;
  __hip_bfloat16* qTb = bfbase + 3*BSLOT;
  __hip_bfloat16* kTb = bfbase + 4*BSLOT;
  __hip_bfloat16* vTb = bfbase + 5*BSLOT;

  // stage 1: x -> q1,k1,v1 (Cin=64)
  ConvArgs a1;
  a1.in0[0]=x; a1.in0[1]=x; a1.in0[2]=x;
  a1.in1[0]=nullptr; a1.in1[1]=nullptr; a1.in1[2]=nullptr;
  a1.w[0]=wq1; a1.w[1]=wk1; a1.w[2]=wv1;
  a1.bias[0]=bq1; a1.bias[1]=bk1; a1.bias[2]=bv1;
  a1.out[0]=s0; a1.out[1]=s1; a1.out[2]=s2;
  a1.cin0=64; a1.cin1=0;
  conv3_relu<<<dim3(BB*64,3), dim3(256), 0, stream>>>(a1);

  // stage 2: -> q,k,v (Cin=32)
  ConvArgs a2;
  a2.in0[0]=s0; a2.in0[1]=s1; a2.in0[2]=s2;
  a2.in1[0]=nullptr; a2.in1[1]=nullptr; a2.in1[2]=nullptr;
  a2.w[0]=wq2; a2.w[1]=wk2; a2.w[2]=wv2;
  a2.bias[0]=bq2; a2.bias[1]=bk2; a2.bias[2]=bv2;
  a2.out[0]=s3; a2.out[1]=s4; a2.out[2]=s5;
  a2.cin0=32; a2.cin1=0;
  conv3_relu<<<dim3(BB*64,3), dim3(256), 0, stream>>>(a2);

  // convert q,k,v to bf16 (direct + transposed)
  cvt_qkv<<<dim3(N_PIX/64, 3, BB), dim3(256), 0, stream>>>(
      s3, s4, s5, qDb, kDb, vDb, qTb, kTb, vTb);

  // attention: 3 passes x 2 batches -> ctx raw into s0,s1,s2
  attn_mfma<<<dim3(N_PIX/32, 3, BB), dim3(256), 0, stream>>>(
      qDb, kDb, vDb, qTb, kTb, vTb, s0, s1, s2);

  // per-pass output convs (Cin=32)  (overwrites bf16 overlay region - done with it)
  ConvArgs a3;
  a3.in0[0]=s0; a3.in0[1]=s1; a3.in0[2]=s2;
  a3.in1[0]=nullptr; a3.in1[1]=nullptr; a3.in1[2]=nullptr;
  a3.w[0]=wr; a3.w[1]=wg; a3.w[2]=wb_;
  a3.bias[0]=br; a3.bias[1]=bg; a3.bias[2]=bb_;
  a3.out[0]=s6; a3.out[1]=s7; a3.out[2]=s8;
  a3.cin0=32; a3.cin1=0;
  conv3_relu<<<dim3(BB*64,3), dim3(256), 0, stream>>>(a3);

  // ctx = (r+g+b)/3 -> s3
  avg3_k<<<dim3((int)(SLOT/256)), dim3(256), 0, stream>>>(s6, s7, s8, s3, (int)SLOT);

  // out = conv(concat(x, ctx), w2)   (Cin = 64 + 32)
  ConvArgs a4;
  a4.in0[0]=x; a4.in0[1]=x; a4.in0[2]=x;
  a4.in1[0]=s3; a4.in1[1]=s3; a4.in1[2]=s3;
  a4.w[0]=w2; a4.w[1]=w2; a4.w[2]=w2;
  a4.bias[0]=b2; a4.bias[1]=b2; a4.bias[2]=b2;
  a4.out[0]=s4; a4.out[1]=s4; a4.out[2]=s4;
  a4.cin0=64; a4.cin1=32;
  conv3_relu<<<dim3(BB*64,1), dim3(256), 0, stream>>>(a4);

  // out = conv(out, w3) -> d_out
  ConvArgs a5;
  a5.in0[0]=s4; a5.in0[1]=s4; a5.in0[2]=s4;
  a5.in1[0]=nullptr; a5.in1[1]=nullptr; a5.in1[2]=nullptr;
  a5.w[0]=w3; a5.w[1]=w3; a5.w[2]=w3;
  a5.bias[0]=b3; a5.bias[1]=b3; a5.bias[2]=b3;
  a5.out[0]=(float*)d_out; a5.out[1]=(float*)d_out; a5.out[2]=(float*)d_out;
  a5.cin0=32; a5.cin1=0;
  conv3_relu<<<dim3(BB*64,1), dim3(256), 0, stream>>>(a5);
}